// Round 7
// baseline (267.238 us; speedup 1.0000x reference)
//
#include <hip/hip_runtime.h>

// FourierFeatureMLP fused kernel for MI355X (gfx950). Round 12.
//
// vs round 11 (176.9 us; MfmaUtil 38, VALUBusy 46.5, VGPR 124, spill-free):
// register margin to the 256-unified budget is ~8 -> only zero-register
// changes allowed. Two applied:
//  * bias via SMEM: bias depends only on hi=lane>>5 -> 2 wave-uniform
//    float4s per slice. Uniform-address reads -> s_load (scalar cache),
//    hoistable to chunk top with NO VGPR cost, + 4 v_cndmask per slice.
//    Deletes the bias-LDS stage AND the kernel's only barrier; LDS 24.6
//    -> 16.4 KB. ds_read latency per slice gone from the critical path.
//  * T5 s_setprio(1/0) around the MFMA pair, tested CLEAN this time
//    (round 10 bundled it with a spill): 2 barrier-free waves/SIMD at
//    drifted phases = the role-diversity regime where T5 pays.
//
// Layouts (32x32x16, learn_hip m74/m101-verified):
//   A: lane holds A[m=lane&31][k=(lane>>5)*8+j]   (W fragment, half8)
//   B: lane holds B[k=(lane>>5)*8+j][n=lane&31]   (h fragment, n=point)
//   D: col(n)=lane&31, row(m)=(reg&3)+8*(reg>>2)+4*(lane>>5)
// Weights fragment-major: frag=((layer*4+c)*2+mm)*16+kt, 1 KB each,
// addr = frag*1024 + lane*16 -> fully-coalesced b128 loads.
// Repack LDS tile [32 rows(pts)][64 units], 16B-chunk XOR swizzle
// c8' = c8 ^ (row&7). Chunk CE produces next-layer h frags 4CE..4CE+3.

#define HDIM   256
#define NLAYER 8
#define PTSW   32
#define NTHR   256
#define TILE_N 128
#define WHALVES (NLAYER * HDIM * HDIM)

typedef __attribute__((ext_vector_type(8))) _Float16 half8;
typedef __attribute__((ext_vector_type(4))) _Float16 half4;
typedef __attribute__((ext_vector_type(2))) _Float16 half2;
typedef __attribute__((ext_vector_type(16))) float f32x16;

__device__ __forceinline__ half2 pk2(float a, float b) {
    return __builtin_bit_cast(half2, __builtin_amdgcn_cvt_pkrtz(a, b));
}

// tanh(acc + b) with pre-scaled bias bK = b * 2/ln2:
// t = acc*K + bK; z = 2^t; r = 1/(1+z); tanh = 1 - 2r. Saturation-safe.
#define TANH_K 2.885390081777927f
__device__ __forceinline__ float fast_tanh_fused(float acc, float bK) {
    float z = __builtin_amdgcn_exp2f(fmaf(acc, TANH_K, bK));
    float r = __builtin_amdgcn_rcpf(z + 1.0f);
    return fmaf(-2.0f, r, 1.0f);
}

__device__ __forceinline__ f32x16 zero16() {
    f32x16 v;
    #pragma unroll
    for (int i = 0; i < 16; ++i) v[i] = 0.f;
    return v;
}

// ---- pre-pass: fp32 -> fp16 weights, FRAGMENT-major for 32x32x16,
// plus pre-scaled f32 bias table bK[layer*256+u] at halfs offset WHALVES.
__global__ void convert_w_kernel(const float* __restrict__ W_in,
                                 const float* __restrict__ W_h,
                                 const float* __restrict__ b_in,
                                 const float* __restrict__ b_h,
                                 _Float16* __restrict__ dst)
{
    const int i = blockIdx.x * blockDim.x + threadIdx.x;   // 0 .. WHALVES-1
    const int j     = i & 7;
    const int lane  = (i >> 3) & 63;
    const int frag  = i >> 9;
    const int kt    = frag & 15;
    const int mm    = (frag >> 4) & 1;
    const int c     = (frag >> 5) & 3;
    const int layer = frag >> 7;
    const int u = c * 64 + mm * 32 + (lane & 31);
    const int k = kt * 16 + (lane >> 5) * 8 + j;
    const float v = (layer == 0) ? W_in[u * HDIM + k]
                                 : W_h[((layer - 1) * HDIM + u) * HDIM + k];
    dst[i] = (_Float16)v;

    if (i < NLAYER * HDIM) {                               // bias table
        float* bk = (float*)(dst + WHALVES);
        const int l = i >> 8, uu = i & 255;
        const float b = (l == 0) ? b_in[uu] : b_h[(l - 1) * HDIM + uu];
        bk[i] = b * TANH_K;
    }
}

// One chunk (64 units, full K=256) = 16 kt x 2 MFMA, with the PREVIOUS
// chunk's (CE) epilogue interleaved: tanh slices kt0-7 (bias via SMEM +
// cndmask), repack ds_reads kt8-11. A-ring: 3 slots, distance-2.
// CE==-1: no epilogue (first chunk of layer 0).
template<int C, int CE>
__device__ __forceinline__ void chunk_step(const _Float16* __restrict__ wl,
                                           const float* __restrict__ bE,  // GLOBAL bias base for CE (uniform)
                                           _Float16* __restrict__ lds,    // wave-private 2048 halfs
                                           const int row, const int hi,
                                           const half8 (&hin)[16],
                                           half8 (&hdst)[16],
                                           f32x16 (&acc)[2],
                                           f32x16 (&accP)[2],
                                           half8 (&A)[3][2])
{
    acc[0] = zero16();
    acc[1] = zero16();

    #pragma unroll
    for (int kt = 0; kt < 16; ++kt) {
        const int idx = C * 16 + kt;
        // distance-2 weight prefetch (VMEM stream = A-loads ONLY)
        if (idx + 2 < 64) {
            const int c2 = (idx + 2) >> 4, k2 = (idx + 2) & 15;
            const int ws = (C + kt + 2) % 3;
            A[ws][0] = *(const half8*)&wl[c2 * 16384 + k2 * 512];
            A[ws][1] = *(const half8*)&wl[c2 * 16384 + 8192 + k2 * 512];
        }

        // ---- epilogue work for chunk CE, before this kt's MFMAs ----
        if constexpr (CE >= 0) {
            if (kt < 8) {                       // tanh slice s=kt: mm, r-group g
                const int mm = kt >> 2, g = kt & 3;
                // bias: wave-uniform address -> s_load; select half by hi
                const float* bu = bE + mm * 32 + g * 8;
                const float bx = hi ? bu[4] : bu[0];
                const float by = hi ? bu[5] : bu[1];
                const float bz = hi ? bu[6] : bu[2];
                const float bw = hi ? bu[7] : bu[3];
                const float v0 = fast_tanh_fused(accP[mm][4 * g + 0], bx);
                const float v1 = fast_tanh_fused(accP[mm][4 * g + 1], by);
                const float v2 = fast_tanh_fused(accP[mm][4 * g + 2], bz);
                const float v3 = fast_tanh_fused(accP[mm][4 * g + 3], bw);
                const half2 lo = pk2(v0, v1);
                const half2 h2 = pk2(v2, v3);
                half4 pkv;
                pkv.x = lo.x; pkv.y = lo.y; pkv.z = h2.x; pkv.w = h2.y;
                const int c8 = 4 * mm + g;      // units c8*8+4*hi .. +3
                *(half4*)&lds[row * 64 + ((c8 ^ (row & 7)) << 3) + hi * 4] = pkv;
            } else if (kt < 12) {               // repack reads q = kt-8
                const int q = kt - 8;
                const int c8r = (2 * q + hi) ^ (row & 7);
                hdst[CE * 4 + q] = *(const half8*)&lds[row * 64 + (c8r << 3)];
            }
        }

        const int slot = (C + kt) % 3;
        __builtin_amdgcn_s_setprio(1);
        acc[0] = __builtin_amdgcn_mfma_f32_32x32x16_f16(A[slot][0], hin[kt], acc[0], 0, 0, 0);
        acc[1] = __builtin_amdgcn_mfma_f32_32x32x16_f16(A[slot][1], hin[kt], acc[1], 0, 0, 0);
        __builtin_amdgcn_s_setprio(0);
    }
}

// Standalone drain of the final layer's chunk 3 -> h frags 12..15.
__device__ __forceinline__ void tail_epilogue(const float* __restrict__ bE,
                                              _Float16* __restrict__ lds,
                                              const int row, const int hi,
                                              f32x16 (&accP)[2],
                                              half8 (&hdst)[16])
{
    #pragma unroll
    for (int s = 0; s < 8; ++s) {
        const int mm = s >> 2, g = s & 3;
        const float* bu = bE + mm * 32 + g * 8;
        const float bx = hi ? bu[4] : bu[0];
        const float by = hi ? bu[5] : bu[1];
        const float bz = hi ? bu[6] : bu[2];
        const float bw = hi ? bu[7] : bu[3];
        const float v0 = fast_tanh_fused(accP[mm][4 * g + 0], bx);
        const float v1 = fast_tanh_fused(accP[mm][4 * g + 1], by);
        const float v2 = fast_tanh_fused(accP[mm][4 * g + 2], bz);
        const float v3 = fast_tanh_fused(accP[mm][4 * g + 3], bw);
        const half2 lo = pk2(v0, v1);
        const half2 h2 = pk2(v2, v3);
        half4 pkv;
        pkv.x = lo.x; pkv.y = lo.y; pkv.z = h2.x; pkv.w = h2.y;
        const int c8 = 4 * mm + g;
        *(half4*)&lds[row * 64 + ((c8 ^ (row & 7)) << 3) + hi * 4] = pkv;
    }
    #pragma unroll
    for (int q = 0; q < 4; ++q) {
        const int c8r = (2 * q + hi) ^ (row & 7);
        hdst[12 + q] = *(const half8*)&lds[row * 64 + (c8r << 3)];
    }
}

__device__ __forceinline__ float dot8(const half8 h, const float4 wa, const float4 wb) {
    return (float)h[0]*wa.x + (float)h[1]*wa.y + (float)h[2]*wa.z + (float)h[3]*wa.w
         + (float)h[4]*wb.x + (float)h[5]*wb.y + (float)h[6]*wb.z + (float)h[7]*wb.w;
}

__global__ __launch_bounds__(NTHR, 2)
void ffmlp_kernel(const float* __restrict__ tx,
                  const float* __restrict__ Bf,
                  const _Float16* __restrict__ Wall,
                  const float* __restrict__ W_out,
                  const float* __restrict__ b_out,
                  float* __restrict__ out)
{
    __shared__ __align__(16) _Float16 lbuf[4][2048];      // 16 KB repack (4 KB/wave)

    const int tid  = threadIdx.x;
    const int wave = tid >> 6;
    const int lane = tid & 63;
    const int row  = lane & 31;          // point within wave tile
    const int hi   = lane >> 5;          // k-half
    const int p0   = blockIdx.x * TILE_N + wave * PTSW;

    const float* bK = (const float*)(Wall + WHALVES);     // global, SMEM-read

    half8 h0[16], h1[16];

    // -------- stage 1: Fourier features directly into B-frag registers ----
    // frag kq holds k = kq*16 + hi*8 + j; kq<8 -> sin(f=k), kq>=8 -> cos.
    // sin(2*pi*r) = v_sin(fract(r)) : argument in revolutions.
    {
        const float2* txv = (const float2*)tx;
        const float2* Bv  = (const float2*)Bf;
        const float2 t = txv[p0 + row];
        #pragma unroll
        for (int kq = 0; kq < 8; ++kq) {
            const int f0 = kq * 16 + hi * 8;
            half8 s8, c8v;
            #pragma unroll
            for (int jj = 0; jj < 8; jj += 2) {
                const float2 bA = Bv[f0 + jj];
                const float2 bB = Bv[f0 + jj + 1];
                const float r0 = __builtin_amdgcn_fractf(t.x * bA.x + t.y * bA.y);
                const float r1 = __builtin_amdgcn_fractf(t.x * bB.x + t.y * bB.y);
                const half2 sp = pk2(__builtin_amdgcn_sinf(r0), __builtin_amdgcn_sinf(r1));
                const half2 cp = pk2(__builtin_amdgcn_cosf(r0), __builtin_amdgcn_cosf(r1));
                s8[jj] = sp.x;  s8[jj + 1] = sp.y;
                c8v[jj] = cp.x; c8v[jj + 1] = cp.y;
            }
            h0[kq]     = s8;
            h0[kq + 8] = c8v;
        }
    }

    // -------- stage 2: 8 dense layers, wave-local, ZERO barriers,
    //          prev-chunk epilogue pipelined into current chunk's K-loop --
    _Float16* __restrict__ lds = &lbuf[wave][0];

    half8  A[3][2];
    f32x16 accA[2], accB[2];

    #pragma unroll 1
    for (int lp = 0; lp < 4; ++lp) {
        const int la = 2 * lp, lb = 2 * lp + 1;
        const _Float16* wla = Wall + la * (HDIM * HDIM) + lane * 8;
        const _Float16* wlb = Wall + lb * (HDIM * HDIM) + lane * 8;

        // ---- even layer: h0 -> h1 ---- (prologue: idx 0,1 -> slots 0,1)
        A[0][0] = *(const half8*)&wla[0];
        A[0][1] = *(const half8*)&wla[8192];
        A[1][0] = *(const half8*)&wla[512];
        A[1][1] = *(const half8*)&wla[8192 + 512];

        if (lp == 0)
            chunk_step<0, -1>(wla, bK, lds, row, hi, h0, h0, accA, accB, A);
        else
            chunk_step<0, 3>(wla, bK + (la - 1) * 256 + 192, lds, row, hi,
                             h0, h0, accA, accB, A);
        chunk_step<1, 0>(wla, bK + la * 256 +   0, lds, row, hi, h0, h1, accB, accA, A);
        chunk_step<2, 1>(wla, bK + la * 256 +  64, lds, row, hi, h0, h1, accA, accB, A);
        chunk_step<3, 2>(wla, bK + la * 256 + 128, lds, row, hi, h0, h1, accB, accA, A);

        // ---- odd layer: h1 -> h0 (chunk0 drains even layer's chunk3) ----
        A[0][0] = *(const half8*)&wlb[0];
        A[0][1] = *(const half8*)&wlb[8192];
        A[1][0] = *(const half8*)&wlb[512];
        A[1][1] = *(const half8*)&wlb[8192 + 512];

        chunk_step<0, 3>(wlb, bK + la * 256 + 192, lds, row, hi, h1, h1, accA, accB, A);
        chunk_step<1, 0>(wlb, bK + lb * 256 +   0, lds, row, hi, h1, h0, accB, accA, A);
        chunk_step<2, 1>(wlb, bK + lb * 256 +  64, lds, row, hi, h1, h0, accA, accB, A);
        chunk_step<3, 2>(wlb, bK + lb * 256 + 128, lds, row, hi, h1, h0, accB, accA, A);
    }
    // drain final layer's chunk 3 into h0 frags 12..15
    tail_epilogue(bK + 7 * 256 + 192, lds, row, hi, accB, h0);

    // -------- stage 3: output matvec from registers ------------------------
    {
        float s = 0.f;
        #pragma unroll
        for (int kq = 0; kq < 16; ++kq) {
            const float4 wa = *(const float4*)&W_out[kq * 16 + hi * 8];
            const float4 wb = *(const float4*)&W_out[kq * 16 + hi * 8 + 4];
            s += dot8(h0[kq], wa, wb);
        }
        s += __shfl_xor(s, 32);              // combine the two k-halves
        if (hi == 0)
            out[p0 + row] = s + b_out[0];
    }
}

extern "C" void kernel_launch(void* const* d_in, const int* in_sizes, int n_in,
                              void* d_out, int out_size, void* d_ws, size_t ws_size,
                              hipStream_t stream) {
    const float* tx    = (const float*)d_in[0];
    const float* Bf    = (const float*)d_in[1];
    const float* W_in  = (const float*)d_in[2];
    const float* b_in  = (const float*)d_in[3];
    const float* W_h   = (const float*)d_in[4];
    const float* b_h   = (const float*)d_in[5];
    const float* W_out = (const float*)d_in[6];
    const float* b_out = (const float*)d_in[7];
    float* out = (float*)d_out;

    _Float16* Wall = (_Float16*)d_ws;   // 1 MiB weights + 8 KB bias table

    const int npts   = in_sizes[0] / 2;
    const int blocks = npts / TILE_N;   // 1024

    convert_w_kernel<<<WHALVES / NTHR, NTHR, 0, stream>>>(W_in, W_h, b_in, b_h, Wall);
    ffmlp_kernel<<<blocks, NTHR, 0, stream>>>(tx, Bf, Wall, W_out, b_out, out);
}

// Round 8
// 244.705 us; speedup vs baseline: 1.0921x; 1.0921x over previous
//
#include <hip/hip_runtime.h>

// FourierFeatureMLP fused kernel for MI355X (gfx950). Round 13.
//
// vs round 12 (227.7 us REGRESSION): the "SMEM bias" read had a
// lane-divergent select on the ADDRESS (hi ? bu[4] : bu[0]) -> compiler
// could not scalarize (SGPR count fell 112->64, i.e. zero s_loads) and
// emitted per-lane 4B VMEM loads -> vmcnt queue polluted again. Fully
// reverted to round 11's bias-in-LDS (176.9 us base).
// vs round 11: ONE isolated zero-register change: T5 s_setprio(1/0)
// around the MFMA pair. Regime fits the catalog's paying case: 2
// barrier-free waves/SIMD drifting through different phases (epilogue
// VALU/trans vs MFMA) -> priority arbitration has roles to separate.
//
// Layouts (32x32x16, learn_hip m74/m101-verified):
//   A: lane holds A[m=lane&31][k=(lane>>5)*8+j]   (W fragment, half8)
//   B: lane holds B[k=(lane>>5)*8+j][n=lane&31]   (h fragment, n=point)
//   D: col(n)=lane&31, row(m)=(reg&3)+8*(reg>>2)+4*(lane>>5)
// Weights fragment-major: frag=((layer*4+c)*2+mm)*16+kt, 1 KB each,
// addr = frag*1024 + lane*16 -> fully-coalesced b128 loads.
// Repack LDS tile [32 rows(pts)][64 units], 16B-chunk XOR swizzle
// c8' = c8 ^ (row&7). Chunk CE produces next-layer h frags 4CE..4CE+3.

#define HDIM   256
#define NLAYER 8
#define PTSW   32
#define NTHR   256
#define TILE_N 128
#define WHALVES (NLAYER * HDIM * HDIM)

typedef __attribute__((ext_vector_type(8))) _Float16 half8;
typedef __attribute__((ext_vector_type(4))) _Float16 half4;
typedef __attribute__((ext_vector_type(2))) _Float16 half2;
typedef __attribute__((ext_vector_type(16))) float f32x16;

__device__ __forceinline__ half2 pk2(float a, float b) {
    return __builtin_bit_cast(half2, __builtin_amdgcn_cvt_pkrtz(a, b));
}

// tanh(acc + b) with pre-scaled bias bK = b * 2/ln2:
// t = acc*K + bK; z = 2^t; r = 1/(1+z); tanh = 1 - 2r. Saturation-safe.
#define TANH_K 2.885390081777927f
__device__ __forceinline__ float fast_tanh_fused(float acc, float bK) {
    float z = __builtin_amdgcn_exp2f(fmaf(acc, TANH_K, bK));
    float r = __builtin_amdgcn_rcpf(z + 1.0f);
    return fmaf(-2.0f, r, 1.0f);
}

__device__ __forceinline__ f32x16 zero16() {
    f32x16 v;
    #pragma unroll
    for (int i = 0; i < 16; ++i) v[i] = 0.f;
    return v;
}

// ---- pre-pass: fp32 -> fp16 weights, FRAGMENT-major for 32x32x16,
// plus pre-scaled f32 bias table bK[layer*256+u] at halfs offset WHALVES.
__global__ void convert_w_kernel(const float* __restrict__ W_in,
                                 const float* __restrict__ W_h,
                                 const float* __restrict__ b_in,
                                 const float* __restrict__ b_h,
                                 _Float16* __restrict__ dst)
{
    const int i = blockIdx.x * blockDim.x + threadIdx.x;   // 0 .. WHALVES-1
    const int j     = i & 7;
    const int lane  = (i >> 3) & 63;
    const int frag  = i >> 9;
    const int kt    = frag & 15;
    const int mm    = (frag >> 4) & 1;
    const int c     = (frag >> 5) & 3;
    const int layer = frag >> 7;
    const int u = c * 64 + mm * 32 + (lane & 31);
    const int k = kt * 16 + (lane >> 5) * 8 + j;
    const float v = (layer == 0) ? W_in[u * HDIM + k]
                                 : W_h[((layer - 1) * HDIM + u) * HDIM + k];
    dst[i] = (_Float16)v;

    if (i < NLAYER * HDIM) {                               // bias table
        float* bk = (float*)(dst + WHALVES);
        const int l = i >> 8, uu = i & 255;
        const float b = (l == 0) ? b_in[uu] : b_h[(l - 1) * HDIM + uu];
        bk[i] = b * TANH_K;
    }
}

// One chunk (64 units, full K=256) = 16 kt x 2 MFMA, with the PREVIOUS
// chunk's (CE) epilogue interleaved: tanh slices kt0-7 (bias from LDS),
// repack ds_reads kt8-11. A-ring: slot (C+kt)%3, distance-2 prefetch.
// CE==-1: no epilogue (first chunk of layer 0).
template<int C, int CE>
__device__ __forceinline__ void chunk_step(const _Float16* __restrict__ wl,
                                           const float* __restrict__ bE,  // LDS bias base for CE
                                           _Float16* __restrict__ lds,    // wave-private 2048 halfs
                                           const int row, const int hi,
                                           const half8 (&hin)[16],
                                           half8 (&hdst)[16],
                                           f32x16 (&acc)[2],
                                           f32x16 (&accP)[2],
                                           half8 (&A)[3][2])
{
    acc[0] = zero16();
    acc[1] = zero16();

    #pragma unroll
    for (int kt = 0; kt < 16; ++kt) {
        const int idx = C * 16 + kt;
        // distance-2 weight prefetch (VMEM stream = A-loads ONLY)
        if (idx + 2 < 64) {
            const int c2 = (idx + 2) >> 4, k2 = (idx + 2) & 15;
            const int ws = (C + kt + 2) % 3;
            A[ws][0] = *(const half8*)&wl[c2 * 16384 + k2 * 512];
            A[ws][1] = *(const half8*)&wl[c2 * 16384 + 8192 + k2 * 512];
        }

        // ---- epilogue work for chunk CE, before this kt's MFMAs ----
        if constexpr (CE >= 0) {
            if (kt < 8) {                       // tanh slice s=kt: mm, r-group g
                const int mm = kt >> 2, g = kt & 3;
                const float4 b4 = *(const float4*)&bE[mm * 32 + g * 8 + hi * 4];
                const float v0 = fast_tanh_fused(accP[mm][4 * g + 0], b4.x);
                const float v1 = fast_tanh_fused(accP[mm][4 * g + 1], b4.y);
                const float v2 = fast_tanh_fused(accP[mm][4 * g + 2], b4.z);
                const float v3 = fast_tanh_fused(accP[mm][4 * g + 3], b4.w);
                const half2 lo = pk2(v0, v1);
                const half2 h2 = pk2(v2, v3);
                half4 pkv;
                pkv.x = lo.x; pkv.y = lo.y; pkv.z = h2.x; pkv.w = h2.y;
                const int c8 = 4 * mm + g;      // units c8*8+4*hi .. +3
                *(half4*)&lds[row * 64 + ((c8 ^ (row & 7)) << 3) + hi * 4] = pkv;
            } else if (kt < 12) {               // repack reads q = kt-8
                const int q = kt - 8;
                const int c8r = (2 * q + hi) ^ (row & 7);
                hdst[CE * 4 + q] = *(const half8*)&lds[row * 64 + (c8r << 3)];
            }
        }

        const int slot = (C + kt) % 3;
        __builtin_amdgcn_s_setprio(1);
        acc[0] = __builtin_amdgcn_mfma_f32_32x32x16_f16(A[slot][0], hin[kt], acc[0], 0, 0, 0);
        acc[1] = __builtin_amdgcn_mfma_f32_32x32x16_f16(A[slot][1], hin[kt], acc[1], 0, 0, 0);
        __builtin_amdgcn_s_setprio(0);
    }
}

// Standalone drain of the final layer's chunk 3 -> h frags 12..15.
__device__ __forceinline__ void tail_epilogue(const float* __restrict__ bE,
                                              _Float16* __restrict__ lds,
                                              const int row, const int hi,
                                              f32x16 (&accP)[2],
                                              half8 (&hdst)[16])
{
    #pragma unroll
    for (int s = 0; s < 8; ++s) {
        const int mm = s >> 2, g = s & 3;
        const float4 b4 = *(const float4*)&bE[mm * 32 + g * 8 + hi * 4];
        const float v0 = fast_tanh_fused(accP[mm][4 * g + 0], b4.x);
        const float v1 = fast_tanh_fused(accP[mm][4 * g + 1], b4.y);
        const float v2 = fast_tanh_fused(accP[mm][4 * g + 2], b4.z);
        const float v3 = fast_tanh_fused(accP[mm][4 * g + 3], b4.w);
        const half2 lo = pk2(v0, v1);
        const half2 h2 = pk2(v2, v3);
        half4 pkv;
        pkv.x = lo.x; pkv.y = lo.y; pkv.z = h2.x; pkv.w = h2.y;
        const int c8 = 4 * mm + g;
        *(half4*)&lds[row * 64 + ((c8 ^ (row & 7)) << 3) + hi * 4] = pkv;
    }
    #pragma unroll
    for (int q = 0; q < 4; ++q) {
        const int c8r = (2 * q + hi) ^ (row & 7);
        hdst[12 + q] = *(const half8*)&lds[row * 64 + (c8r << 3)];
    }
}

__device__ __forceinline__ float dot8(const half8 h, const float4 wa, const float4 wb) {
    return (float)h[0]*wa.x + (float)h[1]*wa.y + (float)h[2]*wa.z + (float)h[3]*wa.w
         + (float)h[4]*wb.x + (float)h[5]*wb.y + (float)h[6]*wb.z + (float)h[7]*wb.w;
}

__global__ __launch_bounds__(NTHR, 2)
void ffmlp_kernel(const float* __restrict__ tx,
                  const float* __restrict__ Bf,
                  const _Float16* __restrict__ Wall,
                  const float* __restrict__ W_out,
                  const float* __restrict__ b_out,
                  float* __restrict__ out)
{
    __shared__ __align__(16) _Float16 lbuf[4][2048];      // 16 KB repack (4 KB/wave)
    __shared__ __align__(16) float    blds[NLAYER * HDIM]; // 8 KB bias

    const int tid  = threadIdx.x;
    const int wave = tid >> 6;
    const int lane = tid & 63;
    const int row  = lane & 31;          // point within wave tile
    const int hi   = lane >> 5;          // k-half
    const int p0   = blockIdx.x * TILE_N + wave * PTSW;

    // -------- stage 0: bias table -> LDS (once; the only barrier) --------
    {
        const float4* s4 = (const float4*)((const float*)(Wall + WHALVES));
        float4* d4 = (float4*)blds;
        d4[tid]       = s4[tid];
        d4[tid + 256] = s4[tid + 256];
    }
    __syncthreads();

    half8 h0[16], h1[16];

    // -------- stage 1: Fourier features directly into B-frag registers ----
    // frag kq holds k = kq*16 + hi*8 + j; kq<8 -> sin(f=k), kq>=8 -> cos.
    // sin(2*pi*r) = v_sin(fract(r)) : argument in revolutions.
    {
        const float2* txv = (const float2*)tx;
        const float2* Bv  = (const float2*)Bf;
        const float2 t = txv[p0 + row];
        #pragma unroll
        for (int kq = 0; kq < 8; ++kq) {
            const int f0 = kq * 16 + hi * 8;
            half8 s8, c8v;
            #pragma unroll
            for (int jj = 0; jj < 8; jj += 2) {
                const float2 bA = Bv[f0 + jj];
                const float2 bB = Bv[f0 + jj + 1];
                const float r0 = __builtin_amdgcn_fractf(t.x * bA.x + t.y * bA.y);
                const float r1 = __builtin_amdgcn_fractf(t.x * bB.x + t.y * bB.y);
                const half2 sp = pk2(__builtin_amdgcn_sinf(r0), __builtin_amdgcn_sinf(r1));
                const half2 cp = pk2(__builtin_amdgcn_cosf(r0), __builtin_amdgcn_cosf(r1));
                s8[jj] = sp.x;  s8[jj + 1] = sp.y;
                c8v[jj] = cp.x; c8v[jj + 1] = cp.y;
            }
            h0[kq]     = s8;
            h0[kq + 8] = c8v;
        }
    }

    // -------- stage 2: 8 dense layers, wave-local, no barriers,
    //          prev-chunk epilogue pipelined into current chunk's K-loop --
    _Float16* __restrict__ lds = &lbuf[wave][0];
    const float* bls = blds;

    half8  A[3][2];
    f32x16 accA[2], accB[2];

    #pragma unroll 1
    for (int lp = 0; lp < 4; ++lp) {
        const int la = 2 * lp, lb = 2 * lp + 1;
        const _Float16* wla = Wall + la * (HDIM * HDIM) + lane * 8;
        const _Float16* wlb = Wall + lb * (HDIM * HDIM) + lane * 8;

        // ---- even layer: h0 -> h1 ---- (prologue: idx 0,1 -> slots 0,1)
        A[0][0] = *(const half8*)&wla[0];
        A[0][1] = *(const half8*)&wla[8192];
        A[1][0] = *(const half8*)&wla[512];
        A[1][1] = *(const half8*)&wla[8192 + 512];

        if (lp == 0)
            chunk_step<0, -1>(wla, bls, lds, row, hi, h0, h0, accA, accB, A);
        else
            chunk_step<0, 3>(wla, bls + (la - 1) * 256 + 192, lds, row, hi,
                             h0, h0, accA, accB, A);
        chunk_step<1, 0>(wla, bls + la * 256 +   0, lds, row, hi, h0, h1, accB, accA, A);
        chunk_step<2, 1>(wla, bls + la * 256 +  64, lds, row, hi, h0, h1, accA, accB, A);
        chunk_step<3, 2>(wla, bls + la * 256 + 128, lds, row, hi, h0, h1, accB, accA, A);

        // ---- odd layer: h1 -> h0 (chunk0 drains even layer's chunk3) ----
        A[0][0] = *(const half8*)&wlb[0];
        A[0][1] = *(const half8*)&wlb[8192];
        A[1][0] = *(const half8*)&wlb[512];
        A[1][1] = *(const half8*)&wlb[8192 + 512];

        chunk_step<0, 3>(wlb, bls + la * 256 + 192, lds, row, hi, h1, h1, accA, accB, A);
        chunk_step<1, 0>(wlb, bls + lb * 256 +   0, lds, row, hi, h1, h0, accB, accA, A);
        chunk_step<2, 1>(wlb, bls + lb * 256 +  64, lds, row, hi, h1, h0, accA, accB, A);
        chunk_step<3, 2>(wlb, bls + lb * 256 + 128, lds, row, hi, h1, h0, accB, accA, A);
    }
    // drain final layer's chunk 3 into h0 frags 12..15
    tail_epilogue(bls + 7 * 256 + 192, lds, row, hi, accB, h0);

    // -------- stage 3: output matvec from registers ------------------------
    {
        float s = 0.f;
        #pragma unroll
        for (int kq = 0; kq < 16; ++kq) {
            const float4 wa = *(const float4*)&W_out[kq * 16 + hi * 8];
            const float4 wb = *(const float4*)&W_out[kq * 16 + hi * 8 + 4];
            s += dot8(h0[kq], wa, wb);
        }
        s += __shfl_xor(s, 32);              // combine the two k-halves
        if (hi == 0)
            out[p0 + row] = s + b_out[0];
    }
}

extern "C" void kernel_launch(void* const* d_in, const int* in_sizes, int n_in,
                              void* d_out, int out_size, void* d_ws, size_t ws_size,
                              hipStream_t stream) {
    const float* tx    = (const float*)d_in[0];
    const float* Bf    = (const float*)d_in[1];
    const float* W_in  = (const float*)d_in[2];
    const float* b_in  = (const float*)d_in[3];
    const float* W_h   = (const float*)d_in[4];
    const float* b_h   = (const float*)d_in[5];
    const float* W_out = (const float*)d_in[6];
    const float* b_out = (const float*)d_in[7];
    float* out = (float*)d_out;

    _Float16* Wall = (_Float16*)d_ws;   // 1 MiB weights + 8 KB bias table

    const int npts   = in_sizes[0] / 2;
    const int blocks = npts / TILE_N;   // 1024

    convert_w_kernel<<<WHALVES / NTHR, NTHR, 0, stream>>>(W_in, W_h, b_in, b_h, Wall);
    ffmlp_kernel<<<blocks, NTHR, 0, stream>>>(tx, Bf, Wall, W_out, b_out, out);
}

// Round 11
// 243.057 us; speedup vs baseline: 1.0995x; 1.0068x over previous
//
#include <hip/hip_runtime.h>

// FourierFeatureMLP fused kernel for MI355X (gfx950). Round 16.
//
// = round 11 VERBATIM (best passing: 176.9 us; MfmaUtil 38.3, VALUBusy
// 46.5, VGPR 124, WRITE_SIZE 512 KB = spill-free). Rounds 12-15 all
// regressed or failed:
//   r12 SMEM-bias: divergent address -> de-scalarized, 227 us. Reverted.
//   r13 s_setprio isolated: -3%. Removed.
//   r14/r15 permlane32_swap repack: absmax 0.51 / 1.55 -- the
//     instruction's lane semantics do not match the documented model
//     under either operand order; algebra itself verified identical to
//     this kernel's working LDS formulas. Abandoned per pre-commitment.
// Remaining levers are evidenced dead ends at this reg-locked structure:
// +8-reg A-ring (r10 spill cliff), conflict-free repack (impossible:
// 16B-aligned strides keep row bits>=3 out of the bank index), T5 (-3%).
//
// Layouts (32x32x16, learn_hip m74/m101-verified):
//   A: lane holds A[m=lane&31][k=(lane>>5)*8+j]   (W fragment, half8)
//   B: lane holds B[k=(lane>>5)*8+j][n=lane&31]   (h fragment, n=point)
//   D: col(n)=lane&31, row(m)=(reg&3)+8*(reg>>2)+4*(lane>>5)
// Weights fragment-major: frag=((layer*4+c)*2+mm)*16+kt, 1 KB each,
// addr = frag*1024 + lane*16 -> fully-coalesced b128 loads.
// Repack LDS tile [32 rows(pts)][64 units], 16B-chunk XOR swizzle
// c8' = c8 ^ (row&7). Chunk CE produces next-layer h frags 4CE..4CE+3.

#define HDIM   256
#define NLAYER 8
#define PTSW   32
#define NTHR   256
#define TILE_N 128
#define WHALVES (NLAYER * HDIM * HDIM)

typedef __attribute__((ext_vector_type(8))) _Float16 half8;
typedef __attribute__((ext_vector_type(4))) _Float16 half4;
typedef __attribute__((ext_vector_type(2))) _Float16 half2;
typedef __attribute__((ext_vector_type(16))) float f32x16;

__device__ __forceinline__ half2 pk2(float a, float b) {
    return __builtin_bit_cast(half2, __builtin_amdgcn_cvt_pkrtz(a, b));
}

// tanh(acc + b) with pre-scaled bias bK = b * 2/ln2:
// t = acc*K + bK; z = 2^t; r = 1/(1+z); tanh = 1 - 2r. Saturation-safe.
#define TANH_K 2.885390081777927f
__device__ __forceinline__ float fast_tanh_fused(float acc, float bK) {
    float z = __builtin_amdgcn_exp2f(fmaf(acc, TANH_K, bK));
    float r = __builtin_amdgcn_rcpf(z + 1.0f);
    return fmaf(-2.0f, r, 1.0f);
}

__device__ __forceinline__ f32x16 zero16() {
    f32x16 v;
    #pragma unroll
    for (int i = 0; i < 16; ++i) v[i] = 0.f;
    return v;
}

// ---- pre-pass: fp32 -> fp16 weights, FRAGMENT-major for 32x32x16,
// plus pre-scaled f32 bias table bK[layer*256+u] at halfs offset WHALVES.
__global__ void convert_w_kernel(const float* __restrict__ W_in,
                                 const float* __restrict__ W_h,
                                 const float* __restrict__ b_in,
                                 const float* __restrict__ b_h,
                                 _Float16* __restrict__ dst)
{
    const int i = blockIdx.x * blockDim.x + threadIdx.x;   // 0 .. WHALVES-1
    const int j     = i & 7;
    const int lane  = (i >> 3) & 63;
    const int frag  = i >> 9;
    const int kt    = frag & 15;
    const int mm    = (frag >> 4) & 1;
    const int c     = (frag >> 5) & 3;
    const int layer = frag >> 7;
    const int u = c * 64 + mm * 32 + (lane & 31);
    const int k = kt * 16 + (lane >> 5) * 8 + j;
    const float v = (layer == 0) ? W_in[u * HDIM + k]
                                 : W_h[((layer - 1) * HDIM + u) * HDIM + k];
    dst[i] = (_Float16)v;

    if (i < NLAYER * HDIM) {                               // bias table
        float* bk = (float*)(dst + WHALVES);
        const int l = i >> 8, uu = i & 255;
        const float b = (l == 0) ? b_in[uu] : b_h[(l - 1) * HDIM + uu];
        bk[i] = b * TANH_K;
    }
}

// One chunk (64 units, full K=256) = 16 kt x 2 MFMA, with the PREVIOUS
// chunk's (CE) epilogue interleaved: tanh slices kt0-7 (bias from LDS),
// repack ds_reads kt8-11. A-ring: slot (C+kt)%3, distance-2 prefetch.
// CE==-1: no epilogue (first chunk of layer 0).
template<int C, int CE>
__device__ __forceinline__ void chunk_step(const _Float16* __restrict__ wl,
                                           const float* __restrict__ bE,  // LDS bias base for CE
                                           _Float16* __restrict__ lds,    // wave-private 2048 halfs
                                           const int row, const int hi,
                                           const half8 (&hin)[16],
                                           half8 (&hdst)[16],
                                           f32x16 (&acc)[2],
                                           f32x16 (&accP)[2],
                                           half8 (&A)[3][2])
{
    acc[0] = zero16();
    acc[1] = zero16();

    #pragma unroll
    for (int kt = 0; kt < 16; ++kt) {
        const int idx = C * 16 + kt;
        // distance-2 weight prefetch (VMEM stream = A-loads ONLY)
        if (idx + 2 < 64) {
            const int c2 = (idx + 2) >> 4, k2 = (idx + 2) & 15;
            const int ws = (C + kt + 2) % 3;
            A[ws][0] = *(const half8*)&wl[c2 * 16384 + k2 * 512];
            A[ws][1] = *(const half8*)&wl[c2 * 16384 + 8192 + k2 * 512];
        }

        // ---- epilogue work for chunk CE, before this kt's MFMAs ----
        if constexpr (CE >= 0) {
            if (kt < 8) {                       // tanh slice s=kt: mm, g
                const int mm = kt >> 2, g = kt & 3;
                const float4 b4 = *(const float4*)&bE[mm * 32 + g * 8 + hi * 4];
                const float v0 = fast_tanh_fused(accP[mm][4 * g + 0], b4.x);
                const float v1 = fast_tanh_fused(accP[mm][4 * g + 1], b4.y);
                const float v2 = fast_tanh_fused(accP[mm][4 * g + 2], b4.z);
                const float v3 = fast_tanh_fused(accP[mm][4 * g + 3], b4.w);
                const half2 lo = pk2(v0, v1);
                const half2 h2 = pk2(v2, v3);
                half4 pkv;
                pkv.x = lo.x; pkv.y = lo.y; pkv.z = h2.x; pkv.w = h2.y;
                const int c8 = 4 * mm + g;      // units c8*8+4*hi .. +3
                *(half4*)&lds[row * 64 + ((c8 ^ (row & 7)) << 3) + hi * 4] = pkv;
            } else if (kt < 12) {               // repack reads q = kt-8
                const int q = kt - 8;
                const int c8r = (2 * q + hi) ^ (row & 7);
                hdst[CE * 4 + q] = *(const half8*)&lds[row * 64 + (c8r << 3)];
            }
        }

        const int slot = (C + kt) % 3;
        acc[0] = __builtin_amdgcn_mfma_f32_32x32x16_f16(A[slot][0], hin[kt], acc[0], 0, 0, 0);
        acc[1] = __builtin_amdgcn_mfma_f32_32x32x16_f16(A[slot][1], hin[kt], acc[1], 0, 0, 0);
    }
}

// Standalone drain of the final layer's chunk 3 -> h frags 12..15.
__device__ __forceinline__ void tail_epilogue(const float* __restrict__ bE,
                                              _Float16* __restrict__ lds,
                                              const int row, const int hi,
                                              f32x16 (&accP)[2],
                                              half8 (&hdst)[16])
{
    #pragma unroll
    for (int s = 0; s < 8; ++s) {
        const int mm = s >> 2, g = s & 3;
        const float4 b4 = *(const float4*)&bE[mm * 32 + g * 8 + hi * 4];
        const float v0 = fast_tanh_fused(accP[mm][4 * g + 0], b4.x);
        const float v1 = fast_tanh_fused(accP[mm][4 * g + 1], b4.y);
        const float v2 = fast_tanh_fused(accP[mm][4 * g + 2], b4.z);
        const float v3 = fast_tanh_fused(accP[mm][4 * g + 3], b4.w);
        const half2 lo = pk2(v0, v1);
        const half2 h2 = pk2(v2, v3);
        half4 pkv;
        pkv.x = lo.x; pkv.y = lo.y; pkv.z = h2.x; pkv.w = h2.y;
        const int c8 = 4 * mm + g;
        *(half4*)&lds[row * 64 + ((c8 ^ (row & 7)) << 3) + hi * 4] = pkv;
    }
    #pragma unroll
    for (int q = 0; q < 4; ++q) {
        const int c8r = (2 * q + hi) ^ (row & 7);
        hdst[12 + q] = *(const half8*)&lds[row * 64 + (c8r << 3)];
    }
}

__device__ __forceinline__ float dot8(const half8 h, const float4 wa, const float4 wb) {
    return (float)h[0]*wa.x + (float)h[1]*wa.y + (float)h[2]*wa.z + (float)h[3]*wa.w
         + (float)h[4]*wb.x + (float)h[5]*wb.y + (float)h[6]*wb.z + (float)h[7]*wb.w;
}

__global__ __launch_bounds__(NTHR, 2)
void ffmlp_kernel(const float* __restrict__ tx,
                  const float* __restrict__ Bf,
                  const _Float16* __restrict__ Wall,
                  const float* __restrict__ W_out,
                  const float* __restrict__ b_out,
                  float* __restrict__ out)
{
    __shared__ __align__(16) _Float16 lbuf[4][2048];      // 16 KB repack (4 KB/wave)
    __shared__ __align__(16) float    blds[NLAYER * HDIM]; // 8 KB bias

    const int tid  = threadIdx.x;
    const int wave = tid >> 6;
    const int lane = tid & 63;
    const int row  = lane & 31;          // point within wave tile
    const int hi   = lane >> 5;          // k-half
    const int p0   = blockIdx.x * TILE_N + wave * PTSW;

    // -------- stage 0: bias table -> LDS (once; the only barrier) --------
    {
        const float4* s4 = (const float4*)((const float*)(Wall + WHALVES));
        float4* d4 = (float4*)blds;
        d4[tid]       = s4[tid];
        d4[tid + 256] = s4[tid + 256];
    }
    __syncthreads();

    half8 h0[16], h1[16];

    // -------- stage 1: Fourier features directly into B-frag registers ----
    // frag kq holds k = kq*16 + hi*8 + j; kq<8 -> sin(f=k), kq>=8 -> cos.
    // sin(2*pi*r) = v_sin(fract(r)) : argument in revolutions.
    {
        const float2* txv = (const float2*)tx;
        const float2* Bv  = (const float2*)Bf;
        const float2 t = txv[p0 + row];
        #pragma unroll
        for (int kq = 0; kq < 8; ++kq) {
            const int f0 = kq * 16 + hi * 8;
            half8 s8, c8v;
            #pragma unroll
            for (int jj = 0; jj < 8; jj += 2) {
                const float2 bA = Bv[f0 + jj];
                const float2 bB = Bv[f0 + jj + 1];
                const float r0 = __builtin_amdgcn_fractf(t.x * bA.x + t.y * bA.y);
                const float r1 = __builtin_amdgcn_fractf(t.x * bB.x + t.y * bB.y);
                const half2 sp = pk2(__builtin_amdgcn_sinf(r0), __builtin_amdgcn_sinf(r1));
                const half2 cp = pk2(__builtin_amdgcn_cosf(r0), __builtin_amdgcn_cosf(r1));
                s8[jj] = sp.x;  s8[jj + 1] = sp.y;
                c8v[jj] = cp.x; c8v[jj + 1] = cp.y;
            }
            h0[kq]     = s8;
            h0[kq + 8] = c8v;
        }
    }

    // -------- stage 2: 8 dense layers, wave-local, no barriers,
    //          prev-chunk epilogue pipelined into current chunk's K-loop --
    _Float16* __restrict__ lds = &lbuf[wave][0];
    const float* bls = blds;

    half8  A[3][2];
    f32x16 accA[2], accB[2];

    #pragma unroll 1
    for (int lp = 0; lp < 4; ++lp) {
        const int la = 2 * lp, lb = 2 * lp + 1;
        const _Float16* wla = Wall + la * (HDIM * HDIM) + lane * 8;
        const _Float16* wlb = Wall + lb * (HDIM * HDIM) + lane * 8;

        // ---- even layer: h0 -> h1 ---- (prologue: idx 0,1 -> slots 0,1)
        A[0][0] = *(const half8*)&wla[0];
        A[0][1] = *(const half8*)&wla[8192];
        A[1][0] = *(const half8*)&wla[512];
        A[1][1] = *(const half8*)&wla[8192 + 512];

        if (lp == 0)
            chunk_step<0, -1>(wla, bls, lds, row, hi, h0, h0, accA, accB, A);
        else
            chunk_step<0, 3>(wla, bls + (la - 1) * 256 + 192, lds, row, hi,
                             h0, h0, accA, accB, A);
        chunk_step<1, 0>(wla, bls + la * 256 +   0, lds, row, hi, h0, h1, accB, accA, A);
        chunk_step<2, 1>(wla, bls + la * 256 +  64, lds, row, hi, h0, h1, accA, accB, A);
        chunk_step<3, 2>(wla, bls + la * 256 + 128, lds, row, hi, h0, h1, accB, accA, A);

        // ---- odd layer: h1 -> h0 (chunk0 drains even layer's chunk3) ----
        A[0][0] = *(const half8*)&wlb[0];
        A[0][1] = *(const half8*)&wlb[8192];
        A[1][0] = *(const half8*)&wlb[512];
        A[1][1] = *(const half8*)&wlb[8192 + 512];

        chunk_step<0, 3>(wlb, bls + la * 256 + 192, lds, row, hi, h1, h1, accA, accB, A);
        chunk_step<1, 0>(wlb, bls + lb * 256 +   0, lds, row, hi, h1, h0, accB, accA, A);
        chunk_step<2, 1>(wlb, bls + lb * 256 +  64, lds, row, hi, h1, h0, accA, accB, A);
        chunk_step<3, 2>(wlb, bls + lb * 256 + 128, lds, row, hi, h1, h0, accB, accA, A);
    }
    // drain final layer's chunk 3 into h0 frags 12..15
    tail_epilogue(bls + 7 * 256 + 192, lds, row, hi, accB, h0);

    // -------- stage 3: output matvec from registers ------------------------
    {
        float s = 0.f;
        #pragma unroll
        for (int kq = 0; kq < 16; ++kq) {
            const float4 wa = *(const float4*)&W_out[kq * 16 + hi * 8];
            const float4 wb = *(const float4*)&W_out[kq * 16 + hi * 8 + 4];
            s += dot8(h0[kq], wa, wb);
        }
        s += __shfl_xor(s, 32);              // combine the two k-halves
        if (hi == 0)
            out[p0 + row] = s + b_out[0];
    }
}

extern "C" void kernel_launch(void* const* d_in, const int* in_sizes, int n_in,
                              void* d_out, int out_size, void* d_ws, size_t ws_size,
                              hipStream_t stream) {
    const float* tx    = (const float*)d_in[0];
    const float* Bf    = (const float*)d_in[1];
    const float* W_in  = (const float*)d_in[2];
    const float* b_in  = (const float*)d_in[3];
    const float* W_h   = (const float*)d_in[4];
    const float* b_h   = (const float*)d_in[5];
    const float* W_out = (const float*)d_in[6];
    const float* b_out = (const float*)d_in[7];
    float* out = (float*)d_out;

    _Float16* Wall = (_Float16*)d_ws;   // 1 MiB weights + 8 KB bias table

    const int npts   = in_sizes[0] / 2;
    const int blocks = npts / TILE_N;   // 1024

    convert_w_kernel<<<WHALVES / NTHR, NTHR, 0, stream>>>(W_in, W_h, b_in, b_h, Wall);
    ffmlp_kernel<<<blocks, NTHR, 0, stream>>>(tx, Bf, Wall, W_out, b_out, out);
}